// Round 3
// baseline (499.138 us; speedup 1.0000x reference)
//
#include <hip/hip_runtime.h>
#include <cstdint>

#define B_N 32
#define C_N 192
#define W_N 56
#define HW_N 3136
#define CO_N 384
#define K_N 384
#define M_N 100352   // B_N * HW_N

typedef unsigned short u16;
typedef unsigned int u32;
typedef __attribute__((ext_vector_type(8))) short short8;
typedef __attribute__((ext_vector_type(4))) float floatx4;

__device__ __forceinline__ u16 bf16rne(float f) {
  union { float f; u32 u; } v; v.f = f;
  u32 r = (v.u + 0x7FFFu + ((v.u >> 16) & 1u)) >> 16;
  return (u16)r;
}

// ============ K0: fold BN consts, convert W to bf16 ============
__global__ __launch_bounds__(256) void prep_consts(
    const float* __restrict__ Wc, const float* __restrict__ bconv,
    const float* __restrict__ gamma, const float* __restrict__ beta,
    const float* __restrict__ rmean, const float* __restrict__ rvar,
    u16* __restrict__ Wbf, float* __restrict__ alphaV, float* __restrict__ betaV) {
  int idx = blockIdx.x * 256 + threadIdx.x;
  if (idx < CO_N * K_N) Wbf[idx] = bf16rne(Wc[idx]);
  if (idx < CO_N) {
    float s = gamma[idx] * rsqrtf(rvar[idx] + 1e-5f);
    alphaV[idx] = s;
    betaV[idx] = bconv[idx] * s + beta[idx] - rmean[idx] * s;
  }
}

// ============ K1: per-(b,c) plane -> xj (bf16), wave-per-plane ============
// No __syncthreads: each wave owns one plane start-to-finish. Plane staged in
// LDS with stride 57 (odd) -> both row scans (addr h*57+lane) and col scans
// (addr lane*57+w, bank 25*lane+w mod 32) are conflict-free. Min structures
// (min1/min2/argmin per (w,hp) and (h,wp)) built in registers, spilled to
// small LDS arrays, read back as aligned float4 in the output pass.
#define PLN_F 3192     // 56*57
#define WSLOT 3864     // PLN_F + 6*112 structure floats

__global__ __launch_bounds__(128) void xj_compute(const float* __restrict__ x,
                                                  u16* __restrict__ XJ) {
  __shared__ float sm[2 * WSLOT];   // 30912 B -> 5 blocks/CU
  int tid = threadIdx.x;
  int wid = tid >> 6, lane = tid & 63;
  float* pl  = sm + wid * WSLOT;
  float* rs1 = pl + PLN_F;          // [2][56] keyed (h-parity, w)
  float* rs2 = rs1 + 112;
  float* rsa = rs2 + 112;           // argmin h as int bits
  float* cs1 = rsa + 112;           // [2][56] keyed (w-parity, h)
  float* cs2 = cs1 + 112;
  float* csa = cs2 + 112;
  size_t base = ((size_t)blockIdx.x * 2 + wid) * HW_N;
  const float4* xg4 = (const float4*)(x + base);

  // ---- load plane (coalesced) into padded LDS ----
  #pragma unroll 1
  for (int i = lane; i < 784; i += 64) {
    float4 v = xg4[i];
    int h = i / 14;                 // 14 float4 per row
    int w0 = (i - h * 14) * 4;
    float* d = pl + h * 57 + w0;
    d[0] = v.x; d[1] = v.y; d[2] = v.z; d[3] = v.w;
  }
  asm volatile("s_waitcnt lgkmcnt(0)" ::: "memory");
  __builtin_amdgcn_wave_barrier();

  // ---- scans: lane w<56 owns column w (row-dir) and row h=lane (col-dir) ----
  if (lane < 56) {
    float m1a = 3e38f, m2a = 3e38f, m1b = 3e38f, m2b = 3e38f;
    int aa = -1, ab = -1;
    #pragma unroll
    for (int h = 0; h < 56; h += 2) {
      float va = pl[h * 57 + lane];
      float vb = pl[(h + 1) * 57 + lane];
      if (va < m1a) { m2a = m1a; m1a = va; aa = h; } else m2a = fminf(m2a, va);
      if (vb < m1b) { m2b = m1b; m1b = vb; ab = h + 1; } else m2b = fminf(m2b, vb);
    }
    rs1[lane] = m1a; rs1[56 + lane] = m1b;
    rs2[lane] = m2a; rs2[56 + lane] = m2b;
    rsa[lane] = __int_as_float(aa); rsa[56 + lane] = __int_as_float(ab);

    m1a = 3e38f; m2a = 3e38f; m1b = 3e38f; m2b = 3e38f; aa = -1; ab = -1;
    const float* rowp = pl + lane * 57;
    #pragma unroll
    for (int w = 0; w < 56; w += 2) {
      float va = rowp[w];
      float vb = rowp[w + 1];
      if (va < m1a) { m2a = m1a; m1a = va; aa = w; } else m2a = fminf(m2a, va);
      if (vb < m1b) { m2b = m1b; m1b = vb; ab = w + 1; } else m2b = fminf(m2b, vb);
    }
    cs1[lane] = m1a; cs1[56 + lane] = m1b;
    cs2[lane] = m2a; cs2[56 + lane] = m2b;
    csa[lane] = __int_as_float(aa); csa[56 + lane] = __int_as_float(ab);
  }
  asm volatile("s_waitcnt lgkmcnt(0)" ::: "memory");
  __builtin_amdgcn_wave_barrier();

  // ---- output pass: quad of pixels per lane-iter, coalesced ushort4 store ----
  u16* op = XJ + base;
  #pragma unroll 1
  for (int i = lane; i < 784; i += 64) {
    int idx = i * 4;
    int h = i / 14;
    int w0 = (i - h * 14) * 4;
    int hp = h & 1;
    const float* pr = pl + h * 57 + w0;
    float4 r1 = *(const float4*)(rs1 + hp * 56 + w0);   // 16B-aligned (w0%4==0)
    float4 r2 = *(const float4*)(rs2 + hp * 56 + w0);
    float4 ra = *(const float4*)(rsa + hp * 56 + w0);
    float c1a = cs1[h], c1b = cs1[56 + h];
    float c2a = cs2[h], c2b = cs2[56 + h];
    int caa = __float_as_int(csa[h]), cab = __float_as_int(csa[56 + h]);
    ushort4 o;
    u16* opx = &o.x;
    const float* r1p = &r1.x; const float* r2p = &r2.x; const float* rap = &ra.x;
    #pragma unroll
    for (int j = 0; j < 4; ++j) {
      int wv = w0 + j;
      float rm = (__float_as_int(rap[j]) == h) ? r2p[j] : r1p[j];
      float cm;
      if ((wv & 1) == 0) cm = (caa == wv) ? c2a : c1a;
      else               cm = (cab == wv) ? c2b : c1b;
      float xj = pr[j] - fminf(rm, cm);
      opx[j] = bf16rne(fmaxf(xj, 0.0f));
    }
    *(ushort4*)(op + idx) = o;
  }
}

// ============ K2: FUSED all-N GEMM (BM=128, BN=384) + BN + GELU ============
// vs R2: (1) Bs LDS staging DELETED -- B fragments load straight from global
// (Wbf is 288 KB, L2-resident; latency hides under the 48 MFMAs), removing
// the stage+vmcnt-drain from every K-step. (2) A-gather software-pipelined:
// pk(ko+1) issues after barrier-2, its HBM latency hides under compute(ko).
// LDS = max(As 16K, epilogue 50688) = 50688 B.

__device__ __forceinline__ void load_pk(int s, u32 pk[2][4],
                                        const float* __restrict__ x,
                                        const u16* __restrict__ XJ,
                                        const u32* offs, int kp) {
  if (s < 3) {
    int c0 = s * 64;
    #pragma unroll
    for (int r = 0; r < 2; ++r) {
      const float* a = x + (size_t)offs[r] + (size_t)(c0 + 2 * kp) * HW_N;
      float4 v0 = *(const float4*)a;
      float4 v1 = *(const float4*)(a + HW_N);
      const float* f0 = &v0.x; const float* f1 = &v1.x;
      #pragma unroll
      for (int j = 0; j < 4; ++j)
        pk[r][j] = (u32)bf16rne(f0[j]) | ((u32)bf16rne(f1[j]) << 16);
    }
  } else {
    int c0 = (s - 3) * 64;
    #pragma unroll
    for (int r = 0; r < 2; ++r) {
      const u16* a = XJ + (size_t)offs[r] + (size_t)(c0 + 2 * kp) * HW_N;
      ushort4 v0 = *(const ushort4*)a;
      ushort4 v1 = *(const ushort4*)(a + HW_N);
      const u16* q0 = &v0.x; const u16* q1 = &v1.x;
      #pragma unroll
      for (int j = 0; j < 4; ++j)
        pk[r][j] = (u32)q0[j] | ((u32)q1[j] << 16);
    }
  }
}

__global__ __launch_bounds__(512, 4) void gemm_fused(
    const float* __restrict__ x, const u16* __restrict__ XJ,
    const u16* __restrict__ Wbf,
    const float* __restrict__ alphaV, const float* __restrict__ betaV,
    float* __restrict__ out) {
  __shared__ __align__(16) char smem_raw[50688]; // As 16K (loop) / ep (epilogue)
  u16* As = (u16*)smem_raw;
  u32* As32 = (u32*)smem_raw;
  float* ep = (float*)smem_raw;
  int tid = threadIdx.x;
  int lane = tid & 63;
  int w = tid >> 6;              // 0..7
  int wm = w & 1, wn = w >> 1;   // 2m x 4n
  int l15 = lane & 15, quad = lane >> 4;
  int m0 = blockIdx.x << 7;

  // A-staging map: kp = channel-pair (0..31), pxq = pixel-quad (0..15)
  int kp = tid >> 4;
  int pxq = tid & 15;
  u32 offs[2];
  #pragma unroll
  for (int r = 0; r < 2; ++r) {
    int gm = m0 + (pxq + 16 * r) * 4;
    int bb = gm / HW_N;
    int pp = gm - bb * HW_N;
    offs[r] = (u32)bb * (u32)(C_N * HW_N) + (u32)pp;
  }

  floatx4 acc[4][6];
  #pragma unroll
  for (int i = 0; i < 4; ++i)
    #pragma unroll
    for (int j = 0; j < 6; ++j) acc[i][j] = (floatx4)0.0f;

  u32 pk[2][4];
  load_pk(0, pk, x, XJ, offs, kp);

  #pragma unroll 1
  for (int ko = 0; ko < 6; ++ko) {
    __syncthreads();               // prior compute done reading As
    #pragma unroll
    for (int r = 0; r < 2; ++r) {
      #pragma unroll
      for (int j = 0; j < 4; ++j) {
        int px = (pxq + 16 * r) * 4 + j;
        As32[px * 32 + (kp & 3) + (((kp >> 2) ^ ((px >> 1) & 7)) << 2)] = pk[r][j];
      }
    }
    __syncthreads();               // As visible
    u32 pkn[2][4];
    if (ko < 5) load_pk(ko + 1, pkn, x, XJ, offs, kp);  // hides under compute
    int k0 = ko * 64;
    #pragma unroll
    for (int h2 = 0; h2 < 2; ++h2) {
      short8 aF[4], bF[6];
      #pragma unroll
      for (int mi = 0; mi < 4; ++mi) {
        int r = wm * 64 + mi * 16 + l15;
        aF[mi] = *(const short8*)(As + r * 64 + (((h2 * 4 + quad) ^ ((r >> 1) & 7)) << 3));
      }
      #pragma unroll
      for (int ni = 0; ni < 6; ++ni) {
        int r = wn * 96 + ni * 16 + l15;
        bF[ni] = *(const short8*)(Wbf + (size_t)r * K_N + k0 + ((h2 * 4 + quad) << 3));
      }
      #pragma unroll
      for (int mi = 0; mi < 4; ++mi)
        #pragma unroll
        for (int ni = 0; ni < 6; ++ni)
          acc[mi][ni] = __builtin_amdgcn_mfma_f32_16x16x32_bf16(
              aF[mi], bF[ni], acc[mi][ni], 0, 0, 0);
    }
    if (ko < 5) {
      #pragma unroll
      for (int r = 0; r < 2; ++r)
        #pragma unroll
        for (int j = 0; j < 4; ++j) pk[r][j] = pkn[r][j];
    }
  }

  // ---- epilogue: BN affine + exact GELU; 4 chunks of 96 o-rows ----
  float av[6], bv[6];
  #pragma unroll
  for (int ni = 0; ni < 6; ++ni) {
    int o = wn * 96 + ni * 16 + l15;
    av[ni] = alphaV[o];
    bv[ni] = betaV[o];
  }
  #pragma unroll 1
  for (int oc = 0; oc < 4; ++oc) {
    __syncthreads();
    if (wn == oc) {          // 2 waves (wm 0/1) own this 96-row chunk
      #pragma unroll
      for (int ni = 0; ni < 6; ++ni) {
        #pragma unroll
        for (int mi = 0; mi < 4; ++mi) {
          floatx4 a = acc[mi][ni];
          float4 g;
          float* gp = &g.x;
          #pragma unroll
          for (int i = 0; i < 4; ++i) {
            float t = a[i] * av[ni] + bv[ni];
            gp[i] = 0.5f * t * (1.0f + erff(t * 0.70710678118654752f));
          }
          *(float4*)&ep[(ni * 16 + l15) * 132 + wm * 64 + mi * 16 + quad * 4] = g;
        }
      }
    }
    __syncthreads();
    #pragma unroll
    for (int it = 0; it < 6; ++it) {
      int task = tid + it * 512;    // 3072 tasks = 96 rows x 32 px-quads
      int r = task >> 5;
      int c4 = task & 31;
      float4 v = *(float4*)&ep[r * 132 + c4 * 4];
      int gm = m0 + c4 * 4;
      int bb = gm / HW_N;
      int pp = gm - bb * HW_N;
      *(float4*)(out + ((size_t)(bb * CO_N + oc * 96 + r)) * HW_N + pp) = v;
    }
  }
}

extern "C" void kernel_launch(void* const* d_in, const int* in_sizes, int n_in,
                              void* d_out, int out_size, void* d_ws, size_t ws_size,
                              hipStream_t stream) {
  const float* x  = (const float*)d_in[0];
  const float* Wc = (const float*)d_in[1];
  const float* bc = (const float*)d_in[2];
  const float* gm = (const float*)d_in[3];
  const float* bt = (const float*)d_in[4];
  const float* rm = (const float*)d_in[5];
  const float* rv = (const float*)d_in[6];
  float* out = (float*)d_out;

  char* ws = (char*)d_ws;
  size_t offXJ = 0;
  size_t offWb = offXJ + (size_t)B_N * C_N * HW_N * 2;
  size_t offAl = offWb + (size_t)CO_N * K_N * 2;
  u16* XJ = (u16*)(ws + offXJ);
  u16* Wbf = (u16*)(ws + offWb);
  float* alphaV = (float*)(ws + offAl);
  float* betaV = alphaV + CO_N;

  hipLaunchKernelGGL(prep_consts, dim3(576), dim3(256), 0, stream,
                     Wc, bc, gm, bt, rm, rv, Wbf, alphaV, betaV);
  hipLaunchKernelGGL(xj_compute, dim3(B_N * C_N / 2), dim3(128), 0, stream, x, XJ);
  hipLaunchKernelGGL(gemm_fused, dim3(M_N / 128), dim3(512), 0, stream,
                     x, XJ, Wbf, alphaV, betaV, out);
}

// Round 4
// 349.639 us; speedup vs baseline: 1.4276x; 1.4276x over previous
//
#include <hip/hip_runtime.h>
#include <cstdint>

#define B_N 32
#define C_N 192
#define W_N 56
#define HW_N 3136
#define CO_N 384
#define K_N 384
#define M_N 100352   // B_N * HW_N

typedef unsigned short u16;
typedef unsigned int u32;
typedef __attribute__((ext_vector_type(8))) short short8;
typedef __attribute__((ext_vector_type(4))) float floatx4;

__device__ __forceinline__ u16 bf16rne(float f) {
  union { float f; u32 u; } v; v.f = f;
  u32 r = (v.u + 0x7FFFu + ((v.u >> 16) & 1u)) >> 16;
  return (u16)r;
}

// ---- direct global->LDS staging (16B/lane). lbase must be wave-uniform. ----
__device__ __forceinline__ void stage16(const void* g, void* lbase, int lane) {
#if __has_builtin(__builtin_amdgcn_global_load_lds)
  __builtin_amdgcn_global_load_lds(
      (const __attribute__((address_space(1))) void*)(uintptr_t)g,
      (__attribute__((address_space(3))) void*)(u32)(uintptr_t)lbase,
      16, 0, 0);
#else
  *(uint4*)((char*)lbase + lane * 16) = *(const uint4*)g;
#endif
}

// ============ K0: fold BN consts, convert W to bf16 ============
__global__ __launch_bounds__(256) void prep_consts(
    const float* __restrict__ Wc, const float* __restrict__ bconv,
    const float* __restrict__ gamma, const float* __restrict__ beta,
    const float* __restrict__ rmean, const float* __restrict__ rvar,
    u16* __restrict__ Wbf, float* __restrict__ alphaV, float* __restrict__ betaV) {
  int idx = blockIdx.x * 256 + threadIdx.x;
  if (idx < CO_N * K_N) Wbf[idx] = bf16rne(Wc[idx]);
  if (idx < CO_N) {
    float s = gamma[idx] * rsqrtf(rvar[idx] + 1e-5f);
    alphaV[idx] = s;
    betaV[idx] = bconv[idx] * s + beta[idx] - rmean[idx] * s;
  }
}

// ============ K1: per-(b,c) plane -> xj (bf16), wave-per-plane ============
// Exclusion-min via VALUE EQUALITY (no argmin): rm = (v==m1) ? m2 : m1.
// Correct under duplicates: if two positions tie at m1, then m2==m1 too.
// Branchless update m2=min(m2,max(m1,v)); m1=min(m1,v): 8 independent
// dep-chains (2 dirs x 2 parities x min1/min2) -> good ILP, no LDS argmin.
// Plane stride 57 (odd): row scan banks (57l+w)%32 = (25l+w)%32 bijective,
// col scan lane-varying -> both conflict-free.
#define PLN_F 3192     // 56*57
#define WSLOT 3640     // PLN_F + 4*112 structure floats

__global__ __launch_bounds__(128) void xj_compute(const float* __restrict__ x,
                                                  u16* __restrict__ XJ) {
  __shared__ float sm[2 * WSLOT];   // 29120 B -> 5 blocks/CU
  int tid = threadIdx.x;
  int wid = tid >> 6, lane = tid & 63;
  float* pl  = sm + wid * WSLOT;
  float* rs1 = pl + PLN_F;          // [2][56] keyed (h-parity, w)
  float* rs2 = rs1 + 112;
  float* cs1 = rs2 + 112;           // [2][56] keyed (w-parity, h)
  float* cs2 = cs1 + 112;
  size_t base = ((size_t)blockIdx.x * 2 + wid) * HW_N;
  const float4* xg4 = (const float4*)(x + base);

  // ---- load plane (coalesced) into padded LDS ----
  #pragma unroll 1
  for (int i = lane; i < 784; i += 64) {
    float4 v = xg4[i];
    int h = i / 14;                 // 14 float4 per row
    int w0 = (i - h * 14) * 4;
    float* d = pl + h * 57 + w0;
    d[0] = v.x; d[1] = v.y; d[2] = v.z; d[3] = v.w;
  }
  asm volatile("s_waitcnt lgkmcnt(0)" ::: "memory");
  __builtin_amdgcn_wave_barrier();

  // ---- scans: lane w<56 owns column w (row-dir) and row h=lane (col-dir) ----
  if (lane < 56) {
    float r1a = 3e38f, r2a = 3e38f, r1b = 3e38f, r2b = 3e38f;
    float c1a = 3e38f, c2a = 3e38f, c1b = 3e38f, c2b = 3e38f;
    const float* rowp = pl + lane * 57;
    #pragma unroll
    for (int i = 0; i < 28; ++i) {
      float va = pl[(2 * i) * 57 + lane];
      float vb = pl[(2 * i + 1) * 57 + lane];
      float wa = rowp[2 * i];
      float wb = rowp[2 * i + 1];
      r2a = fminf(r2a, fmaxf(r1a, va)); r1a = fminf(r1a, va);
      r2b = fminf(r2b, fmaxf(r1b, vb)); r1b = fminf(r1b, vb);
      c2a = fminf(c2a, fmaxf(c1a, wa)); c1a = fminf(c1a, wa);
      c2b = fminf(c2b, fmaxf(c1b, wb)); c1b = fminf(c1b, wb);
    }
    rs1[lane] = r1a; rs1[56 + lane] = r1b;
    rs2[lane] = r2a; rs2[56 + lane] = r2b;
    cs1[lane] = c1a; cs1[56 + lane] = c1b;
    cs2[lane] = c2a; cs2[56 + lane] = c2b;
  }
  asm volatile("s_waitcnt lgkmcnt(0)" ::: "memory");
  __builtin_amdgcn_wave_barrier();

  // ---- output pass: quad of pixels per lane-iter, coalesced ushort4 store ----
  u16* op = XJ + base;
  #pragma unroll 1
  for (int i = lane; i < 784; i += 64) {
    int idx = i * 4;
    int h = i / 14;
    int w0 = (i - h * 14) * 4;
    int hp = h & 1;
    const float* pr = pl + h * 57 + w0;
    float4 s1 = *(const float4*)(rs1 + hp * 56 + w0);   // 16B-aligned
    float4 s2 = *(const float4*)(rs2 + hp * 56 + w0);
    float c1e = cs1[h], c1o = cs1[56 + h];
    float c2e = cs2[h], c2o = cs2[56 + h];
    ushort4 o;
    u16* opx = &o.x;
    const float* s1p = &s1.x; const float* s2p = &s2.x;
    #pragma unroll
    for (int j = 0; j < 4; ++j) {
      int wv = w0 + j;
      float v = pr[j];
      float rm = (v == s1p[j]) ? s2p[j] : s1p[j];
      float cm;
      if ((wv & 1) == 0) cm = (v == c1e) ? c2e : c1e;
      else               cm = (v == c1o) ? c2o : c1o;
      float xj = v - fminf(rm, cm);
      opx[j] = bf16rne(fmaxf(xj, 0.0f));
    }
    *(ushort4*)(op + idx) = o;
  }
}

// ============ K2: FUSED all-N GEMM (BM=128, BN=384) + BN + GELU ============
// R2 structure (proven 146 us): Bs via global_load_lds + XOR swizzle (B lines
// amortized wave-wide, L2-served), As built in-LDS from x/XJ. Plus R3's
// register A-prefetch: pk(ko+1) global->reg issues under compute(ko), hiding
// the scattered A-gather latency that was R2's exposed chain.

__device__ __forceinline__ void load_pk(int s, u32 pk[2][4],
                                        const float* __restrict__ x,
                                        const u16* __restrict__ XJ,
                                        const u32* offs, int kp) {
  if (s < 3) {
    int c0 = s * 64;
    #pragma unroll
    for (int r = 0; r < 2; ++r) {
      const float* a = x + (size_t)offs[r] + (size_t)(c0 + 2 * kp) * HW_N;
      float4 v0 = *(const float4*)a;
      float4 v1 = *(const float4*)(a + HW_N);
      const float* f0 = &v0.x; const float* f1 = &v1.x;
      #pragma unroll
      for (int j = 0; j < 4; ++j)
        pk[r][j] = (u32)bf16rne(f0[j]) | ((u32)bf16rne(f1[j]) << 16);
    }
  } else {
    int c0 = (s - 3) * 64;
    #pragma unroll
    for (int r = 0; r < 2; ++r) {
      const u16* a = XJ + (size_t)offs[r] + (size_t)(c0 + 2 * kp) * HW_N;
      ushort4 v0 = *(const ushort4*)a;
      ushort4 v1 = *(const ushort4*)(a + HW_N);
      const u16* q0 = &v0.x; const u16* q1 = &v1.x;
      #pragma unroll
      for (int j = 0; j < 4; ++j)
        pk[r][j] = (u32)q0[j] | ((u32)q1[j] << 16);
    }
  }
}

__global__ __launch_bounds__(512) void gemm_fused(
    const float* __restrict__ x, const u16* __restrict__ XJ,
    const u16* __restrict__ Wbf,
    const float* __restrict__ alphaV, const float* __restrict__ betaV,
    float* __restrict__ out) {
  __shared__ __align__(16) char smem_raw[65536]; // As 16K + Bs 48K; ep 50688 B
  u16* As = (u16*)smem_raw;
  u32* As32 = (u32*)smem_raw;
  u16* Bs = (u16*)(smem_raw + 16384);
  float* ep = (float*)smem_raw;
  int tid = threadIdx.x;
  int lane = tid & 63;
  int w = tid >> 6;              // 0..7
  int wm = w & 1, wn = w >> 1;   // 2m x 4n
  int l15 = lane & 15, quad = lane >> 4;
  int m0 = blockIdx.x << 7;

  // A-staging map: kp = channel-pair (0..31), pxq = pixel-quad (0..15)
  int kp = tid >> 4;
  int pxq = tid & 15;
  u32 offs[2];
  #pragma unroll
  for (int r = 0; r < 2; ++r) {
    int gm = m0 + (pxq + 16 * r) * 4;
    int bb = gm / HW_N;
    int pp = gm - bb * HW_N;
    offs[r] = (u32)bb * (u32)(C_N * HW_N) + (u32)pp;
  }
  // Bs staging map: wave w owns rows w*48..w*48+47 (6 calls x 8 rows)
  int lrow = lane >> 3;
  int lchunk = lane & 7;

  floatx4 acc[4][6];
  #pragma unroll
  for (int i = 0; i < 4; ++i)
    #pragma unroll
    for (int j = 0; j < 6; ++j) acc[i][j] = (floatx4)0.0f;

  u32 pk[2][4];
  load_pk(0, pk, x, XJ, offs, kp);

  #pragma unroll 1
  for (int ko = 0; ko < 6; ++ko) {
    int c0 = (ko < 3 ? ko * 64 : (ko - 3) * 64);
    int kbase = (ko < 3 ? 0 : 192);
    __syncthreads();               // prior compute done reading As/Bs
    #pragma unroll
    for (int c = 0; c < 6; ++c) {  // stage all 384 B-rows for this K-step
      int rowbase = w * 48 + c * 8;
      int row = rowbase + lrow;
      int chunk = lchunk ^ (row & 7);
      stage16(Wbf + (size_t)row * K_N + kbase + c0 + chunk * 8,
              Bs + rowbase * 64, lane);
    }
    #pragma unroll
    for (int r = 0; r < 2; ++r) {
      #pragma unroll
      for (int j = 0; j < 4; ++j) {
        int px = (pxq + 16 * r) * 4 + j;
        As32[px * 32 + (kp & 3) + (((kp >> 2) ^ ((px >> 1) & 7)) << 2)] = pk[r][j];
      }
    }
    __syncthreads();               // As/Bs visible (drains vmcnt+lgkm)
    u32 pkn[2][4];
    if (ko < 5) load_pk(ko + 1, pkn, x, XJ, offs, kp);  // hides under compute
    #pragma unroll
    for (int h2 = 0; h2 < 2; ++h2) {
      short8 aF[4], bF[6];
      #pragma unroll
      for (int mi = 0; mi < 4; ++mi) {
        int r = wm * 64 + mi * 16 + l15;
        aF[mi] = *(const short8*)(As + r * 64 + (((h2 * 4 + quad) ^ ((r >> 1) & 7)) << 3));
      }
      #pragma unroll
      for (int ni = 0; ni < 6; ++ni) {
        int r = wn * 96 + ni * 16 + l15;
        bF[ni] = *(const short8*)(Bs + r * 64 + (((h2 * 4 + quad) ^ (r & 7)) << 3));
      }
      #pragma unroll
      for (int mi = 0; mi < 4; ++mi)
        #pragma unroll
        for (int ni = 0; ni < 6; ++ni)
          acc[mi][ni] = __builtin_amdgcn_mfma_f32_16x16x32_bf16(
              aF[mi], bF[ni], acc[mi][ni], 0, 0, 0);
    }
    if (ko < 5) {
      #pragma unroll
      for (int r = 0; r < 2; ++r)
        #pragma unroll
        for (int j = 0; j < 4; ++j) pk[r][j] = pkn[r][j];
    }
  }

  // ---- epilogue: BN affine + exact GELU; 4 chunks of 96 o-rows ----
  float av[6], bv[6];
  #pragma unroll
  for (int ni = 0; ni < 6; ++ni) {
    int o = wn * 96 + ni * 16 + l15;
    av[ni] = alphaV[o];
    bv[ni] = betaV[o];
  }
  #pragma unroll 1
  for (int oc = 0; oc < 4; ++oc) {
    __syncthreads();
    if (wn == oc) {          // 2 waves (wm 0/1) own this 96-row chunk
      #pragma unroll
      for (int ni = 0; ni < 6; ++ni) {
        #pragma unroll
        for (int mi = 0; mi < 4; ++mi) {
          floatx4 a = acc[mi][ni];
          float4 g;
          float* gp = &g.x;
          #pragma unroll
          for (int i = 0; i < 4; ++i) {
            float t = a[i] * av[ni] + bv[ni];
            gp[i] = 0.5f * t * (1.0f + erff(t * 0.70710678118654752f));
          }
          *(float4*)&ep[(ni * 16 + l15) * 132 + wm * 64 + mi * 16 + quad * 4] = g;
        }
      }
    }
    __syncthreads();
    #pragma unroll
    for (int it = 0; it < 6; ++it) {
      int task = tid + it * 512;    // 3072 tasks = 96 rows x 32 px-quads
      int r = task >> 5;
      int c4 = task & 31;
      float4 v = *(float4*)&ep[r * 132 + c4 * 4];
      int gm = m0 + c4 * 4;
      int bb = gm / HW_N;
      int pp = gm - bb * HW_N;
      *(float4*)(out + ((size_t)(bb * CO_N + oc * 96 + r)) * HW_N + pp) = v;
    }
  }
}

extern "C" void kernel_launch(void* const* d_in, const int* in_sizes, int n_in,
                              void* d_out, int out_size, void* d_ws, size_t ws_size,
                              hipStream_t stream) {
  const float* x  = (const float*)d_in[0];
  const float* Wc = (const float*)d_in[1];
  const float* bc = (const float*)d_in[2];
  const float* gm = (const float*)d_in[3];
  const float* bt = (const float*)d_in[4];
  const float* rm = (const float*)d_in[5];
  const float* rv = (const float*)d_in[6];
  float* out = (float*)d_out;

  char* ws = (char*)d_ws;
  size_t offXJ = 0;
  size_t offWb = offXJ + (size_t)B_N * C_N * HW_N * 2;
  size_t offAl = offWb + (size_t)CO_N * K_N * 2;
  u16* XJ = (u16*)(ws + offXJ);
  u16* Wbf = (u16*)(ws + offWb);
  float* alphaV = (float*)(ws + offAl);
  float* betaV = alphaV + CO_N;

  hipLaunchKernelGGL(prep_consts, dim3(576), dim3(256), 0, stream,
                     Wc, bc, gm, bt, rm, rv, Wbf, alphaV, betaV);
  hipLaunchKernelGGL(xj_compute, dim3(B_N * C_N / 2), dim3(128), 0, stream, x, XJ);
  hipLaunchKernelGGL(gemm_fused, dim3(M_N / 128), dim3(512), 0, stream,
                     x, XJ, Wbf, alphaV, betaV, out);
}

// Round 5
// 332.843 us; speedup vs baseline: 1.4996x; 1.0505x over previous
//
#include <hip/hip_runtime.h>
#include <cstdint>

#define B_N 32
#define C_N 192
#define W_N 56
#define HW_N 3136
#define CO_N 384
#define K_N 384
#define M_N 100352   // B_N * HW_N
#define ST_F 448     // structure floats per plane: rs1[112] rs2[112] cs1[112] cs2[112]

typedef unsigned short u16;
typedef unsigned int u32;
typedef __attribute__((ext_vector_type(8))) short short8;
typedef __attribute__((ext_vector_type(2))) unsigned int u32x2;
typedef __attribute__((ext_vector_type(4))) float floatx4;

__device__ __forceinline__ u16 bf16rne(float f) {
  union { float f; u32 u; } v; v.f = f;
  u32 r = (v.u + 0x7FFFu + ((v.u >> 16) & 1u)) >> 16;
  return (u16)r;
}

// ---- direct global->LDS staging (16B/lane). lbase must be wave-uniform. ----
__device__ __forceinline__ void stage16(const void* g, void* lbase, int lane) {
#if __has_builtin(__builtin_amdgcn_global_load_lds)
  __builtin_amdgcn_global_load_lds(
      (const __attribute__((address_space(1))) void*)(uintptr_t)g,
      (__attribute__((address_space(3))) void*)(u32)(uintptr_t)lbase,
      16, 0, 0);
#else
  *(uint4*)((char*)lbase + lane * 16) = *(const uint4*)g;
#endif
}

// ============ K0: fold BN consts, convert W to bf16 (K-PERMUTED) ============
// Packed k index K = 64*ko + t, t in [0,64):
//   t&3 in {0,1} -> source x-channel  ch = 32*ko + 2*(t>>2) + (t&1)
//   t&3 in {2,3} -> source xj-channel ch (orig col ch+192)
// This interleave lets the GEMM emit the x-slot and xj-slot of a channel
// pair as ONE adjacent 8-byte LDS write after a single x read.
__global__ __launch_bounds__(256) void prep_consts(
    const float* __restrict__ Wc, const float* __restrict__ bconv,
    const float* __restrict__ gamma, const float* __restrict__ beta,
    const float* __restrict__ rmean, const float* __restrict__ rvar,
    u16* __restrict__ Wbf, float* __restrict__ alphaV, float* __restrict__ betaV) {
  int idx = blockIdx.x * 256 + threadIdx.x;
  if (idx < CO_N * K_N) {
    int o = idx / K_N, K = idx - o * K_N;
    int ko = K >> 6, t = K & 63;
    int ch = 32 * ko + 2 * (t >> 2) + (t & 1);
    int src = ch + ((t & 2) ? 192 : 0);
    Wbf[idx] = bf16rne(Wc[o * K_N + src]);
  }
  if (idx < CO_N) {
    float s = gamma[idx] * rsqrtf(rvar[idx] + 1e-5f);
    alphaV[idx] = s;
    betaV[idx] = bconv[idx] * s + beta[idx] - rmean[idx] * s;
  }
}

// ============ K1: per-(b,c) plane -> min-structures ONLY (448 floats) ============
// XJ is never materialized. Structure layout per plane (float idx):
//   [0:112)   rs1[hp][w]  min1 over column w, rows of parity hp
//   [112:224) rs2[hp][w]  min2
//   [224:336) cs1[h][wp]  min1 over row h, cols of parity wp  (pairs: 2h+wp)
//   [336:448) cs2[h][wp]  min2
// One plane per 128-thr block: wave0 does row-dir (56 cols), wave1 col-dir
// (56 rows). Plane in LDS stride 57 (odd -> both scan patterns conflict-free).
#define PLN_F 3192     // 56*57

__global__ __launch_bounds__(128) void struct_compute(const float* __restrict__ x,
                                                      float* __restrict__ ST) {
  __shared__ float pl[PLN_F];
  int tid = threadIdx.x;
  size_t pbase = (size_t)blockIdx.x * HW_N;
  const float4* xg4 = (const float4*)(x + pbase);
  #pragma unroll 1
  for (int i = tid; i < 784; i += 128) {
    float4 v = xg4[i];
    int h = i / 14;
    int w0 = (i - h * 14) * 4;
    float* d = pl + h * 57 + w0;
    d[0] = v.x; d[1] = v.y; d[2] = v.z; d[3] = v.w;
  }
  __syncthreads();
  float* st = ST + (size_t)blockIdx.x * ST_F;
  if (tid < 56) {                       // row-dir: column w = tid
    float r1a = 3e38f, r2a = 3e38f, r1b = 3e38f, r2b = 3e38f;
    #pragma unroll
    for (int i = 0; i < 28; ++i) {
      float va = pl[(2 * i) * 57 + tid];
      float vb = pl[(2 * i + 1) * 57 + tid];
      r2a = fminf(r2a, fmaxf(r1a, va)); r1a = fminf(r1a, va);
      r2b = fminf(r2b, fmaxf(r1b, vb)); r1b = fminf(r1b, vb);
    }
    st[tid] = r1a;       st[56 + tid] = r1b;
    st[112 + tid] = r2a; st[168 + tid] = r2b;
  } else if (tid >= 64 && tid < 120) {  // col-dir: row h = tid-64
    int h = tid - 64;
    const float* rowp = pl + h * 57;
    float c1a = 3e38f, c2a = 3e38f, c1b = 3e38f, c2b = 3e38f;
    #pragma unroll
    for (int i = 0; i < 28; ++i) {
      float wa = rowp[2 * i];
      float wb = rowp[2 * i + 1];
      c2a = fminf(c2a, fmaxf(c1a, wa)); c1a = fminf(c1a, wa);
      c2b = fminf(c2b, fmaxf(c1b, wb)); c1b = fminf(c1b, wb);
    }
    st[224 + 2 * h] = c1a; st[225 + 2 * h] = c1b;
    st[336 + 2 * h] = c2a; st[337 + 2 * h] = c2b;
  }
}

// ============ K2: FUSED all-N GEMM + on-the-fly xj + BN + GELU ============
// Thread map: cp = tid>>5 (channel pair, 16), pxq = tid&31 (pixel quad, 32).
// Per K-step each thread reads x float4 v0,v1 (channels 2cp,2cp+1; 32 lanes
// x 16B = 512B contiguous), loads 8 small structure values (L2), computes
// xj = max(0, v - min(rm,cm)) with the value-equality exclusion trick, and
// writes {x-pair, xj-pair} as ONE b64 to As. Slot s_x=2cp, s_j=2cp+1 share
// chunk (cp>>1)^((px>>1)&7) -> adjacent words; read side identical to R4.

__global__ __launch_bounds__(512) void gemm_fused(
    const float* __restrict__ x, const float* __restrict__ ST,
    const u16* __restrict__ Wbf,
    const float* __restrict__ alphaV, const float* __restrict__ betaV,
    float* __restrict__ out) {
  __shared__ __align__(16) char smem_raw[65536]; // As 16K + Bs 48K; ep 50688 B
  u16* As = (u16*)smem_raw;
  u32* As32 = (u32*)smem_raw;
  u16* Bs = (u16*)(smem_raw + 16384);
  float* ep = (float*)smem_raw;
  int tid = threadIdx.x;
  int lane = tid & 63;
  int w = tid >> 6;              // 0..7
  int wm = w & 1, wn = w >> 1;   // 2m x 4n
  int l15 = lane & 15, quad = lane >> 4;
  int m0 = blockIdx.x << 7;

  // ---- A map: cp = channel-pair (0..15), pxq = pixel-quad (0..31) ----
  int cp = tid >> 5;
  int pxq = tid & 31;
  int gm = m0 + pxq * 4;
  int bb = gm / HW_N;
  int pp = gm - bb * HW_N;
  int hh = pp / W_N;
  int w0 = pp - hh * W_N;        // multiple of 4
  int hp = hh & 1;
  const float* xbase = x + (size_t)bb * (C_N * HW_N) + pp;
  const float* stbase = ST + (size_t)bb * (C_N * ST_F);
  int hpw = hp * 56 + w0;
  int csoff = 224 + 2 * hh;

  // Bs staging map: wave w owns rows w*48..w*48+47 (6 calls x 8 rows)
  int lrow = lane >> 3;
  int lchunk = lane & 7;

  floatx4 acc[4][6];
  #pragma unroll
  for (int i = 0; i < 4; ++i)
    #pragma unroll
    for (int j = 0; j < 6; ++j) acc[i][j] = (floatx4)0.0f;

  u32 pkx[4], pkj[4];
  // ---- prefetch+pack for K-step s: x once -> both x-slots and xj-slots ----
  auto load_pk = [&](int s, u32* ox, u32* oj) {
    int ch0 = 32 * s + 2 * cp;
    const float* xa = xbase + (size_t)ch0 * HW_N;
    float4 v0 = *(const float4*)xa;
    float4 v1 = *(const float4*)(xa + HW_N);
    const float* sb0 = stbase + (size_t)ch0 * ST_F;
    const float* sb1 = sb0 + ST_F;
    float4 r10 = *(const float4*)(sb0 + hpw);
    float4 r20 = *(const float4*)(sb0 + 112 + hpw);
    float2 c10 = *(const float2*)(sb0 + csoff);
    float2 c20 = *(const float2*)(sb0 + csoff + 112);
    float4 r11 = *(const float4*)(sb1 + hpw);
    float4 r21 = *(const float4*)(sb1 + 112 + hpw);
    float2 c11 = *(const float2*)(sb1 + csoff);
    float2 c21 = *(const float2*)(sb1 + csoff + 112);
    const float* f0 = &v0.x; const float* f1 = &v1.x;
    const float* r10p = &r10.x; const float* r20p = &r20.x;
    const float* r11p = &r11.x; const float* r21p = &r21.x;
    #pragma unroll
    for (int j = 0; j < 4; ++j) {
      float a = f0[j], b = f1[j];
      ox[j] = (u32)bf16rne(a) | ((u32)bf16rne(b) << 16);
      float rm0 = (a == r10p[j]) ? r20p[j] : r10p[j];
      float rm1 = (b == r11p[j]) ? r21p[j] : r11p[j];
      float cm0, cm1;
      if ((j & 1) == 0) {
        cm0 = (a == c10.x) ? c20.x : c10.x;
        cm1 = (b == c11.x) ? c21.x : c11.x;
      } else {
        cm0 = (a == c10.y) ? c20.y : c10.y;
        cm1 = (b == c11.y) ? c21.y : c11.y;
      }
      float xj0 = fmaxf(a - fminf(rm0, cm0), 0.0f);
      float xj1 = fmaxf(b - fminf(rm1, cm1), 0.0f);
      oj[j] = (u32)bf16rne(xj0) | ((u32)bf16rne(xj1) << 16);
    }
  };

  load_pk(0, pkx, pkj);

  #pragma unroll 1
  for (int ko = 0; ko < 6; ++ko) {
    __syncthreads();               // prior compute done reading As/Bs
    #pragma unroll
    for (int c = 0; c < 6; ++c) {  // stage all 384 B-rows for this K-step
      int rowbase = w * 48 + c * 8;
      int row = rowbase + lrow;
      int chunk = lchunk ^ (row & 7);
      stage16(Wbf + (size_t)row * K_N + ko * 64 + chunk * 8,
              Bs + rowbase * 64, lane);
    }
    #pragma unroll
    for (int j = 0; j < 4; ++j) {
      int px = pxq * 4 + j;
      int chunk = (cp >> 1) ^ ((px >> 1) & 7);
      u32x2 d; d.x = pkx[j]; d.y = pkj[j];
      *(u32x2*)(As32 + px * 32 + chunk * 4 + 2 * (cp & 1)) = d;
    }
    __syncthreads();               // As/Bs visible (drains vmcnt+lgkm)
    u32 pnx[4], pnj[4];
    if (ko < 5) load_pk(ko + 1, pnx, pnj);   // hides under compute
    #pragma unroll
    for (int h2 = 0; h2 < 2; ++h2) {
      short8 aF[4], bF[6];
      #pragma unroll
      for (int mi = 0; mi < 4; ++mi) {
        int r = wm * 64 + mi * 16 + l15;
        aF[mi] = *(const short8*)(As + r * 64 + (((h2 * 4 + quad) ^ ((r >> 1) & 7)) << 3));
      }
      #pragma unroll
      for (int ni = 0; ni < 6; ++ni) {
        int r = wn * 96 + ni * 16 + l15;
        bF[ni] = *(const short8*)(Bs + r * 64 + (((h2 * 4 + quad) ^ (r & 7)) << 3));
      }
      #pragma unroll
      for (int mi = 0; mi < 4; ++mi)
        #pragma unroll
        for (int ni = 0; ni < 6; ++ni)
          acc[mi][ni] = __builtin_amdgcn_mfma_f32_16x16x32_bf16(
              aF[mi], bF[ni], acc[mi][ni], 0, 0, 0);
    }
    if (ko < 5) {
      #pragma unroll
      for (int j = 0; j < 4; ++j) { pkx[j] = pnx[j]; pkj[j] = pnj[j]; }
    }
  }

  // ---- epilogue: BN affine + exact GELU; 4 chunks of 96 o-rows ----
  float av[6], bv[6];
  #pragma unroll
  for (int ni = 0; ni < 6; ++ni) {
    int o = wn * 96 + ni * 16 + l15;
    av[ni] = alphaV[o];
    bv[ni] = betaV[o];
  }
  #pragma unroll 1
  for (int oc = 0; oc < 4; ++oc) {
    __syncthreads();
    if (wn == oc) {          // 2 waves (wm 0/1) own this 96-row chunk
      #pragma unroll
      for (int ni = 0; ni < 6; ++ni) {
        #pragma unroll
        for (int mi = 0; mi < 4; ++mi) {
          floatx4 a = acc[mi][ni];
          float4 g;
          float* gp = &g.x;
          #pragma unroll
          for (int i = 0; i < 4; ++i) {
            float t = a[i] * av[ni] + bv[ni];
            gp[i] = 0.5f * t * (1.0f + erff(t * 0.70710678118654752f));
          }
          *(float4*)&ep[(ni * 16 + l15) * 132 + wm * 64 + mi * 16 + quad * 4] = g;
        }
      }
    }
    __syncthreads();
    #pragma unroll
    for (int it = 0; it < 6; ++it) {
      int task = tid + it * 512;    // 3072 tasks = 96 rows x 32 px-quads
      int r = task >> 5;
      int c4 = task & 31;
      float4 v = *(float4*)&ep[r * 132 + c4 * 4];
      int g = m0 + c4 * 4;
      int b2 = g / HW_N;
      int p2 = g - b2 * HW_N;
      *(float4*)(out + ((size_t)(b2 * CO_N + oc * 96 + r)) * HW_N + p2) = v;
    }
  }
}

extern "C" void kernel_launch(void* const* d_in, const int* in_sizes, int n_in,
                              void* d_out, int out_size, void* d_ws, size_t ws_size,
                              hipStream_t stream) {
  const float* x  = (const float*)d_in[0];
  const float* Wc = (const float*)d_in[1];
  const float* bc = (const float*)d_in[2];
  const float* gm = (const float*)d_in[3];
  const float* bt = (const float*)d_in[4];
  const float* rm = (const float*)d_in[5];
  const float* rv = (const float*)d_in[6];
  float* out = (float*)d_out;

  char* ws = (char*)d_ws;
  size_t offST = 0;
  size_t offWb = offST + (size_t)B_N * C_N * ST_F * 4;
  size_t offAl = offWb + (size_t)CO_N * K_N * 2;
  float* ST = (float*)(ws + offST);
  u16* Wbf = (u16*)(ws + offWb);
  float* alphaV = (float*)(ws + offAl);
  float* betaV = alphaV + CO_N;

  hipLaunchKernelGGL(prep_consts, dim3(576), dim3(256), 0, stream,
                     Wc, bc, gm, bt, rm, rv, Wbf, alphaV, betaV);
  hipLaunchKernelGGL(struct_compute, dim3(B_N * C_N), dim3(128), 0, stream, x, ST);
  hipLaunchKernelGGL(gemm_fused, dim3(M_N / 128), dim3(512), 0, stream,
                     x, ST, Wbf, alphaV, betaV, out);
}